// Round 16
// baseline (210.750 us; speedup 1.0000x reference)
//
#include <hip/hip_runtime.h>
#include <hip/hip_bf16.h>
#include <math.h>

#define NH 8
#define HD 64
#define CH 512
#define NT 1024
#define NB 8

typedef __bf16 bf16_t;
typedef bf16_t bf16x8 __attribute__((ext_vector_type(8)));
typedef bf16_t bf16x4 __attribute__((ext_vector_type(4)));
typedef float  f32x4  __attribute__((ext_vector_type(4)));
typedef float  f32x16 __attribute__((ext_vector_type(16)));
typedef unsigned u32x4 __attribute__((ext_vector_type(4)));

#define MFMA16(a, b, c) __builtin_amdgcn_mfma_f32_16x16x32_bf16((a), (b), (c), 0, 0, 0)
#define MFMA32(a, b, c) __builtin_amdgcn_mfma_f32_32x32x16_bf16((a), (b), (c), 0, 0, 0)
#define EXP2(x) __builtin_amdgcn_exp2f(x)

__device__ __forceinline__ void gload16(const void* g, void* l) {
    __builtin_amdgcn_global_load_lds(
        (const __attribute__((address_space(1))) void*)g,
        (__attribute__((address_space(3))) void*)l, 16, 0, 0);
}

// pack two f32 -> one dword of 2x bf16 (no builtin on gfx950; T12 recipe)
__device__ __forceinline__ unsigned cvtpk(float lo, float hi) {
    unsigned r;
    asm("v_cvt_pk_bf16_f32 %0, %1, %2" : "=v"(r) : "v"(lo), "v"(hi));
    return r;
}

// v_permlane32_swap_b32: a' = {a.lo32, b.lo32}, b' = {a.hi32, b.hi32}
__device__ __forceinline__ void plswap(unsigned& a, unsigned& b) {
    asm("v_permlane32_swap_b32 %0, %1" : "+v"(a), "+v"(b));
}

// ---------------------------------------------------------------------------
// prep: fp32 [C][N] -> bf16 [N][C] transpose (per 64x64 tile).
// grid (128, 24): x = tile (c-tile = x&7, n-tile = x>>3); y: b = y/3, ft = y%3
// ---------------------------------------------------------------------------
__global__ __launch_bounds__(256) void prep_kernel(
    const float* __restrict__ fc, const float* __restrict__ fp,
    const float* __restrict__ fn, bf16_t* __restrict__ Xc,
    bf16_t* __restrict__ Xn)
{
    __shared__ __align__(16) bf16_t tile[64 * 64];
    const int t = threadIdx.x;
    const int y = blockIdx.y;
    const int b = y / 3, ft = y % 3;
    const int c0 = (blockIdx.x & 7) * 64;
    const int n0 = (blockIdx.x >> 3) * 64;

    const float* src; bf16_t* dst;
    if (ft == 0)      { src = fc + (size_t)b * CH * NT; dst = Xc + (size_t)b * NT * CH; }
    else if (ft == 1) { src = fp + (size_t)b * CH * NT; dst = Xn + (size_t)b * 2 * NT * CH; }
    else              { src = fn + (size_t)b * CH * NT; dst = Xn + (size_t)b * 2 * NT * CH + (size_t)NT * CH; }

    const int nb = t & 15, cb = t >> 4;   // 4-wide chunks
    float4 ld[4];
#pragma unroll
    for (int i = 0; i < 4; ++i)
        ld[i] = *(const float4*)(src + (size_t)(c0 + cb * 4 + i) * NT + n0 + nb * 4);
    const float* lf = (const float*)ld;
#pragma unroll
    for (int j = 0; j < 4; ++j) {
        int n = nb * 4 + j;
        int v = (n >> 2) & 14;            // even -> bf16x8 readback stays contiguous
        bf16x4 wv = { (bf16_t)lf[0 * 4 + j], (bf16_t)lf[1 * 4 + j],
                      (bf16_t)lf[2 * 4 + j], (bf16_t)lf[3 * 4 + j] };
        *(bf16x4*)(tile + n * 64 + ((cb ^ v) * 4)) = wv;
    }
    __syncthreads();
#pragma unroll
    for (int i = 0; i < 2; ++i) {
        int gid = t + i * 256;            // 512 chunks of 16B
        int n = gid >> 3, c16 = gid & 7;
        int v = (n >> 2) & 14;
        bf16x8 val = *(const bf16x8*)(tile + n * 64 + (((2 * c16) ^ v) * 4));
        *(bf16x8*)(dst + (size_t)(n0 + n) * CH + c0 + c16 * 8) = val;
    }
}

// weights fp32 -> bf16, grid (256, 4); also zeroes the LN sum/sumsq buffers
__global__ __launch_bounds__(256) void wcvt_kernel(
    const float* __restrict__ Wq, const float* __restrict__ Wk,
    const float* __restrict__ Wv, const float* __restrict__ Wo,
    bf16_t* __restrict__ Wb, float* __restrict__ SQz)
{
    const int m = blockIdx.y;
    const float* src = (m == 0) ? Wq : (m == 1) ? Wk : (m == 2) ? Wv : Wo;
    bf16_t* dst = Wb + (size_t)m * CH * CH;
    int gid = blockIdx.x * 256 + threadIdx.x;      // 65536 float4 per matrix
    float4 v = *(const float4*)(src + (size_t)gid * 4);
    bf16x4 o = { (bf16_t)v.x, (bf16_t)v.y, (bf16_t)v.z, (bf16_t)v.w };
    *(bf16x4*)(dst + (size_t)gid * 4) = o;
    if (m == 0 && blockIdx.x < 16) {               // 16*256*16B = 64KB (sum+sumsq)
        f32x4 zz = {0.f, 0.f, 0.f, 0.f};
        *(f32x4*)(SQz + (size_t)(blockIdx.x * 256 + threadIdx.x) * 4) = zz;
    }
}

// ---------------------------------------------------------------------------
// gemm_core v6: 128x128 tile, K=512, BK=32, double-buffered LDS staging --
// ONE barrier per K-step: stage(kt+1) issued first, compute on buf[kt&1],
// barrier drains gloads + protects buffer reuse.  LDS: 4 x 8KB.
// ---------------------------------------------------------------------------
template <bool SWAP>
__device__ __forceinline__ void gemm_core(const bf16_t* __restrict__ A,
                                          const bf16_t* __restrict__ B,
                                          bf16_t* aT0, bf16_t* bT0,
                                          bf16_t* aT1, bf16_t* bT1,
                                          f32x4 acc[4][4])
{
    const int t = threadIdx.x, w = t >> 6, lane = t & 63;
    const int lid = lane & 15, quad = lane >> 4;
    const int wm = w >> 1, wn = w & 1;
    const int l4 = lane >> 2, k4 = lane & 3;

#define GSTAGE(k0, aT, bT)                                                     \
    {                                                                          \
        _Pragma("unroll")                                                      \
        for (int i = 0; i < 2; ++i) {                                          \
            int q = w * 2 + i;                       /* chunk 0..7 */          \
            int row = q * 16 + l4;                                             \
            int kk = k4 ^ ((row >> 1) & 3);                                    \
            gload16(A + (size_t)row * CH + (k0) + kk * 8, (aT) + q * 512);     \
            gload16(B + (size_t)row * CH + (k0) + kk * 8, (bT) + q * 512);     \
        }                                                                      \
    }

    GSTAGE(0, aT0, bT0);
    __syncthreads();

    for (int kt = 0; kt < 16; ++kt) {
        const int cur = kt & 1;
        const bf16_t* aTr = cur ? aT1 : aT0;
        const bf16_t* bTr = cur ? bT1 : bT0;
        if (kt < 15) {
            bf16_t* aTw = cur ? aT0 : aT1;
            bf16_t* bTw = cur ? bT0 : bT1;
            GSTAGE((kt + 1) * 32, aTw, bTw);
        }

        const bf16_t* mT = SWAP ? bTr : aTr;
        const bf16_t* nT = SWAP ? aTr : bTr;
        bf16x8 mf[4], nf[4];
#pragma unroll
        for (int i = 0; i < 4; ++i) {
            int row = wm * 64 + i * 16 + lid;
            int kw = quad ^ ((row >> 1) & 3);
            mf[i] = *(const bf16x8*)(mT + row * 32 + kw * 8);
        }
#pragma unroll
        for (int i = 0; i < 4; ++i) {
            int row = wn * 64 + i * 16 + lid;
            int kw = quad ^ ((row >> 1) & 3);
            nf[i] = *(const bf16x8*)(nT + row * 32 + kw * 8);
        }
        __builtin_amdgcn_s_setprio(1);
#pragma unroll
        for (int mi = 0; mi < 4; ++mi)
#pragma unroll
            for (int ni = 0; ni < 4; ++ni)
                acc[mi][ni] = MFMA16(mf[mi], nf[ni], acc[mi][ni]);
        __builtin_amdgcn_s_setprio(0);
        __syncthreads();   // drains next-tile gloads; buffers swap safely
    }
#undef GSTAGE
}

// ---------------------------------------------------------------------------
// qkv: grid (160, 8).  bx<32: Q; 32..95: K; 96..159: V (SWAP, writes Vt[co][key])
// ---------------------------------------------------------------------------
__global__ __launch_bounds__(256) void qkv_kernel(
    const bf16_t* __restrict__ Xc, const bf16_t* __restrict__ Xn,
    const bf16_t* __restrict__ Wb,
    bf16_t* __restrict__ Qn, bf16_t* __restrict__ Kn, bf16_t* __restrict__ Vt)
{
    __shared__ __align__(16) bf16_t aT0[128 * 32];
    __shared__ __align__(16) bf16_t bT0[128 * 32];
    __shared__ __align__(16) bf16_t aT1[128 * 32];
    __shared__ __align__(16) bf16_t bT1[128 * 32];
    const int bx = blockIdx.x, b = blockIdx.y;
    const int t = threadIdx.x, w = t >> 6, lane = t & 63;
    const int lid = lane & 15, quad = lane >> 4;
    const int wm = w >> 1, wn = w & 1;
    const float QSC = 0.125f * 1.44269504f;

    f32x4 acc[4][4] = {};

    if (bx < 96) {                        // Q or K job
        const bf16_t* A; const bf16_t* B; bf16_t* O; float scale;
        if (bx < 32) {
            int nt = bx >> 2, ct = bx & 3;
            A = Xc + (size_t)b * NT * CH + (size_t)nt * 128 * CH;
            B = Wb + (size_t)0 * CH * CH + (size_t)ct * 128 * CH;
            O = Qn + (size_t)b * NT * CH + (size_t)nt * 128 * CH + ct * 128;
            scale = QSC;
        } else {
            int j = bx - 32, nt = j >> 2, ct = j & 3;
            A = Xn + (size_t)b * 2 * NT * CH + (size_t)nt * 128 * CH;
            B = Wb + (size_t)1 * CH * CH + (size_t)ct * 128 * CH;
            O = Kn + (size_t)b * 2 * NT * CH + (size_t)nt * 128 * CH + ct * 128;
            scale = 1.0f;
        }
        gemm_core<false>(A, B, aT0, bT0, aT1, bT1, acc);
#pragma unroll
        for (int mi = 0; mi < 4; ++mi)
#pragma unroll
            for (int ni = 0; ni < 4; ++ni)
#pragma unroll
                for (int r = 0; r < 4; ++r) {
                    int n  = wm * 64 + mi * 16 + quad * 4 + r;
                    int co = wn * 64 + ni * 16 + lid;
                    O[(size_t)n * CH + co] = (bf16_t)(acc[mi][ni][r] * scale);
                }
    } else {                              // V job -> Vt[co][key]
        int j = bx - 96, nt = j >> 2, ct = j & 3;
        const bf16_t* A = Xn + (size_t)b * 2 * NT * CH + (size_t)nt * 128 * CH;
        const bf16_t* B = Wb + (size_t)2 * CH * CH + (size_t)ct * 128 * CH;
        bf16_t* O = Vt + (size_t)b * CH * 2 * NT + (size_t)ct * 128 * 2 * NT + nt * 128;
        gemm_core<true>(A, B, aT0, bT0, aT1, bT1, acc);
#pragma unroll
        for (int mi = 0; mi < 4; ++mi)
#pragma unroll
            for (int ni = 0; ni < 4; ++ni)
#pragma unroll
                for (int r = 0; r < 4; ++r) {
                    int co_l  = wm * 64 + mi * 16 + quad * 4 + r;
                    int key_l = wn * 64 + ni * 16 + lid;
                    O[(size_t)co_l * (2 * NT) + key_l] = (bf16_t)acc[mi][ni][r];
                }
    }
}

// ---------------------------------------------------------------------------
// attn v7: occupancy fix. 64-q blocks, 64-key tiles, 32 iters, LDS 32KB ->
// 4 blocks/CU (16 waves/CU, was 8). Waves: 2wq (32 q) x 2wk (32 keys).
// Same coalesced gload_lds staging + XOR-swizzled ds_read + 1 barrier/iter
// + in-register softmax (cvt_pk+permlane) as v5a.
// ---------------------------------------------------------------------------
__global__ __launch_bounds__(256, 4) void attn_kernel(
    const bf16_t* __restrict__ Qn, const bf16_t* __restrict__ Kn,
    const bf16_t* __restrict__ Vt, bf16_t* __restrict__ AOn)
{
    __shared__ __align__(16) char smem[32768];
    bf16_t* const kbuf0 = (bf16_t*)smem;             // [64 key][64 d]
    bf16_t* const kbuf1 = (bf16_t*)(smem + 8192);
    bf16_t* const vbuf0 = (bf16_t*)(smem + 16384);   // [64 d][64 key]
    bf16_t* const vbuf1 = (bf16_t*)(smem + 24576);
    // epilogue overlays (used only after the main loop's final barrier):
    float*  const scr_all = (float*)smem;            // 2 x 2176 f32 (17408B)
    bf16_t* const obuf    = (bf16_t*)(smem + 17920); // [64][72] bf16 (9216B)
    float*  const l_scr   = (float*)(smem + 27136);  // 64 f32

    const int t = threadIdx.x;
    const int w = t >> 6, lane = t & 63;
    const int wq = w >> 1, wk = w & 1;
    const int l31 = lane & 31, h = lane >> 5;

    // grid 1024: all 16 q-tiles of one (b,h) share one XCD's L2.
    const int bid = blockIdx.x;
    const int xcd = bid & 7, ii = bid >> 3;          // ii: 0..127
    const int grp = xcd * 8 + (ii >> 4);             // 0..63
    const int qt  = ii & 15;
    const int b = grp >> 3, hh = grp & 7;
    const int q0 = qt * 64;

    const bf16_t* Qb  = Qn + ((size_t)b * NT + q0) * CH + hh * HD;
    const bf16_t* Kb  = Kn + (size_t)b * 2 * NT * CH + hh * HD;
    const bf16_t* Vtb = Vt + ((size_t)b * CH + hh * HD) * (2 * NT);
    bf16_t* AOb = AOn + ((size_t)b * NT + q0) * CH + hh * HD;

    // ---- staging: K tile 512 chunks, V tile 512 chunks (2 each/thread) ----
    // K LDS [64 key][64 d]: chunk c -> row c>>3, granule c&7; src d-granule
    // pre-swizzled ^(row&7).  V LDS [64 d][64 key]: row c>>3 (d), granule
    // c&7 (8 keys), src key-granule pre-swizzled ^(row&7).
#define STAGE_KV(kbn, kw, vw)                                                  \
    {                                                                          \
        _Pragma("unroll")                                                      \
        for (int i = 0; i < 2; ++i) {                                          \
            int ck = w * 64 + i * 256 + lane;                                  \
            int kr = ck >> 3, kg = ck & 7;                                     \
            gload16(Kb + (size_t)((kbn) + kr) * CH + ((kg ^ (kr & 7)) * 8),    \
                    (kw) + (w * 64 + i * 256) * 8);                            \
            gload16(Vtb + (size_t)kr * (2 * NT) + (kbn) + ((kg ^ (kr & 7)) * 8), \
                    (vw) + (w * 64 + i * 256) * 8);                            \
        }                                                                      \
    }

    // Q fragments: gathered once (one-time cost). wq picks 32-q half.
    const bf16_t* Qrow = Qb + (size_t)(wq * 32 + l31) * CH + h * 8;
    bf16x8 qf[4];
#pragma unroll
    for (int ks = 0; ks < 4; ++ks)
        qf[ks] = *(const bf16x8*)(Qrow + ks * 16);

    // prologue: stage tile 0 into buf 0
    STAGE_KV(0, kbuf0, vbuf0);
    __syncthreads();

    f32x16 o[2] = {};          // [df] : d = df*32 + ...
    float lpart = 0.f;

    for (int kt = 0; kt < 32; ++kt) {
        const int cur = kt & 1;
        const bf16_t* const kr_buf = cur ? kbuf1 : kbuf0;
        const bf16_t* const vr_buf = cur ? vbuf1 : vbuf0;
        bf16_t* const kw_buf = cur ? kbuf0 : kbuf1;
        bf16_t* const vw_buf = cur ? vbuf0 : vbuf1;

        // issue next tile's staging first (lands during compute below)
        if (kt < 31)
            STAGE_KV((kt + 1) * 64, kw_buf, vw_buf);

        // ---- K fragments from LDS (swizzled b128 reads) ------------------
        const int krow = wk * 32 + l31;
        bf16x8 kfm[4];
#pragma unroll
        for (int ks = 0; ks < 4; ++ks)
            kfm[ks] = *(const bf16x8*)(kr_buf + krow * 64 + (((ks * 2 + h) ^ (krow & 7)) * 8));

        f32x16 s = {};
        __builtin_amdgcn_s_setprio(1);
#pragma unroll
        for (int ks = 0; ks < 4; ++ks)
            s = MFMA32(kfm[ks], qf[ks], s);
        __builtin_amdgcn_s_setprio(0);

        // ---- softmax in registers -> PV B-fragments ----------------------
        float p[16];
#pragma unroll
        for (int r = 0; r < 16; ++r) p[r] = EXP2(s[r]);
        lpart += ((p[0] + p[1]) + (p[2] + p[3]))
               + ((p[4] + p[5]) + (p[6] + p[7]))
               + ((p[8] + p[9]) + (p[10] + p[11]))
               + ((p[12] + p[13]) + (p[14] + p[15]));
        unsigned a0 = cvtpk(p[0], p[1]),   b0 = cvtpk(p[4], p[5]);
        unsigned a1 = cvtpk(p[2], p[3]),   b1 = cvtpk(p[6], p[7]);
        unsigned a2 = cvtpk(p[8], p[9]),   b2 = cvtpk(p[12], p[13]);
        unsigned a3 = cvtpk(p[10], p[11]), b3 = cvtpk(p[14], p[15]);
        plswap(a0, b0); plswap(a1, b1); plswap(a2, b2); plswap(a3, b3);
        u32x4 f0 = { a0, a1, b0, b1 };
        u32x4 f1 = { a2, a3, b2, b3 };
        bf16x8 pfrag0 = __builtin_bit_cast(bf16x8, f0);
        bf16x8 pfrag1 = __builtin_bit_cast(bf16x8, f1);

        // ---- PV (V fragments from LDS); key = wk*32 + fi*16 + h*8 + e ----
        __builtin_amdgcn_s_setprio(1);
#pragma unroll
        for (int fi = 0; fi < 2; ++fi) {
            const bf16x8 pf = fi ? pfrag1 : pfrag0;
            bf16x8 av[2];
#pragma unroll
            for (int df = 0; df < 2; ++df) {
                int vrow = df * 32 + l31;
                int g = wk * 4 + fi * 2 + h;
                av[df] = *(const bf16x8*)(vr_buf + vrow * 64 + ((g ^ (vrow & 7)) * 8));
            }
#pragma unroll
            for (int df = 0; df < 2; ++df)
                o[df] = MFMA32(av[df], pf, o[df]);
        }
        __builtin_amdgcn_s_setprio(0);
        __syncthreads();   // drains next-tile gloads; LDS bufs swap safely
    }
#undef STAGE_KV

    // ---- epilogue: combine wk halves, normalize, store --------------------
    float l2 = lpart + __shfl_xor(lpart, 32);

    if (wk == 1) {
        float* scr = scr_all + wq * 2176;
#pragma unroll
        for (int df = 0; df < 2; ++df)
#pragma unroll
            for (int g = 0; g < 4; ++g) {
                int d = df * 32 + 8 * g + 4 * h;
                f32x4 v = { o[df][4 * g + 0], o[df][4 * g + 1],
                            o[df][4 * g + 2], o[df][4 * g + 3] };
                *(f32x4*)(scr + l31 * 68 + d) = v;
            }
        if (h == 0) l_scr[wq * 32 + l31] = l2;
    }
    __syncthreads();

    if (wk == 0) {
        const float* scr = scr_all + wq * 2176;
        float inv = 1.0f / (l2 + l_scr[wq * 32 + l31]);
#pragma unroll
        for (int df = 0; df < 2; ++df)
#pragma unroll
            for (int g = 0; g < 4; ++g) {
                int d = df * 32 + 8 * g + 4 * h;
                f32x4 part = *(const f32x4*)(scr + l31 * 68 + d);
                bf16x4 ov = {
                    (bf16_t)((o[df][4 * g + 0] + part.x) * inv),
                    (bf16_t)((o[df][4 * g + 1] + part.y) * inv),
                    (bf16_t)((o[df][4 * g + 2] + part.z) * inv),
                    (bf16_t)((o[df][4 * g + 3] + part.w) * inv) };
                int qg = wq * 32 + l31;
                *(bf16x4*)(obuf + qg * 72 + (d ^ (qg & 24))) = ov;
            }
    }
    __syncthreads();

#pragma unroll
    for (int i = 0; i < 2; ++i) {
        int gid = t + i * 256;            // 512 chunks: 64 rows x 8 granules
        int qr = gid >> 3, c8 = (gid & 7) * 8;
        *(bf16x8*)(AOb + (size_t)qr * CH + c8) =
            *(const bf16x8*)(obuf + qr * 72 + (c8 ^ (qr & 24)));
    }
}

// ---------------------------------------------------------------------------
// proj: Z^T[b][co][n] = (AO @ Wo^T)^T + f_curr[b][co][n]  (fp32). grid (32, 8)
// Fused LN stats: block reduces its 128-co slab per n, atomicAdd sum/sumsq.
// ---------------------------------------------------------------------------
__global__ __launch_bounds__(256) void proj_kernel(
    const bf16_t* __restrict__ AOn, const bf16_t* __restrict__ Wb,
    const float* __restrict__ fc, float* __restrict__ Zt,
    float* __restrict__ Ssum, float* __restrict__ Ssq)
{
    __shared__ __align__(16) bf16_t aT0[128 * 32];
    __shared__ __align__(16) bf16_t bT0[128 * 32];
    __shared__ __align__(16) bf16_t aT1[128 * 32];
    __shared__ __align__(16) bf16_t bT1[128 * 32];
    const int bx = blockIdx.x, b = blockIdx.y;
    const int nt = bx >> 2, ct = bx & 3;
    const int t = threadIdx.x, w = t >> 6, lane = t & 63;
    const int lid = lane & 15, quad = lane >> 4;
    const int wm = w >> 1, wn = w & 1;

    const bf16_t* A = AOn + (size_t)b * NT * CH + (size_t)nt * 128 * CH;
    const bf16_t* B = Wb + (size_t)3 * CH * CH + (size_t)ct * 128 * CH;   // Wo

    f32x4 acc[4][4] = {};
    gemm_core<true>(A, B, aT0, bT0, aT1, bT1, acc);

    const size_t bofs = (size_t)b * CH * NT;
    float sP[4] = {0.f, 0.f, 0.f, 0.f}, qP[4] = {0.f, 0.f, 0.f, 0.f};
#pragma unroll
    for (int mi = 0; mi < 4; ++mi)
#pragma unroll
        for (int ni = 0; ni < 4; ++ni)
#pragma unroll
            for (int r = 0; r < 4; ++r) {
                int co_l = wm * 64 + mi * 16 + quad * 4 + r;
                int n_l  = wn * 64 + ni * 16 + lid;
                size_t idx = bofs + (size_t)(ct * 128 + co_l) * NT + nt * 128 + n_l;
                float z = acc[mi][ni][r] + fc[idx];
                Zt[idx] = z;
                sP[ni] += z;
                qP[ni] += z * z;
            }
    // reduce over quad (co sub-blocks) within wave
#pragma unroll
    for (int ni = 0; ni < 4; ++ni) {
        sP[ni] += __shfl_xor(sP[ni], 16);  sP[ni] += __shfl_xor(sP[ni], 32);
        qP[ni] += __shfl_xor(qP[ni], 16);  qP[ni] += __shfl_xor(qP[ni], 32);
    }
    __syncthreads();                      // all frag reads of LDS done
    float* sRed = (float*)aT0;            // 256 f32
    float* qRed = sRed + 256;
    if (quad == 0) {
#pragma unroll
        for (int ni = 0; ni < 4; ++ni) {
            sRed[w * 64 + ni * 16 + lid] = sP[ni];
            qRed[w * 64 + ni * 16 + lid] = qP[ni];
        }
    }
    __syncthreads();
    if (t < 128) {                        // n_l = t; waves w=wn and w=2+wn
        float s = sRed[t] + sRed[128 + t];
        float q = qRed[t] + qRed[128 + t];
        atomicAdd(&Ssum[(size_t)b * NT + nt * 128 + t], s);
        atomicAdd(&Ssq [(size_t)b * NT + nt * 128 + t], q);
    }
}

// ---------------------------------------------------------------------------
// apply: out[b][co][n] = (z - mu[n]) * rs[n] * gamma[co] + beta[co].
// mu/rs computed inline from fused sum/sumsq.
// ---------------------------------------------------------------------------
__global__ __launch_bounds__(256) void apply_kernel(
    const float* __restrict__ Zt, const float* __restrict__ Ssum,
    const float* __restrict__ Ssq, const float* __restrict__ gamma,
    const float* __restrict__ beta, float* __restrict__ out)
{
    const int row = blockIdx.x;           // b*512 + co
    const int co = row & 511, b = row >> 9;
    const int t = threadIdx.x;
    const float g = gamma[co], be = beta[co];
    const size_t base = (size_t)row * NT + t * 4;
    f32x4 z  = *(const f32x4*)(Zt + base);
    f32x4 S  = *(const f32x4*)(Ssum + (size_t)b * NT + t * 4);
    f32x4 Q2 = *(const f32x4*)(Ssq  + (size_t)b * NT + t * 4);
    f32x4 o;
#pragma unroll
    for (int c = 0; c < 4; ++c) {
        float mu  = S[c] * (1.0f / 512.0f);
        float var = Q2[c] * (1.0f / 512.0f) - mu * mu;
        float rs  = rsqrtf(var + 1e-5f);
        o[c] = (z[c] - mu) * rs * g + be;
    }
    *(f32x4*)(out + base) = o;
}

// ---------------------------------------------------------------------------
extern "C" void kernel_launch(void* const* d_in, const int* in_sizes, int n_in,
                              void* d_out, int out_size, void* d_ws, size_t ws_size,
                              hipStream_t stream)
{
    (void)in_sizes; (void)n_in; (void)out_size; (void)ws_size;
    const float* fc    = (const float*)d_in[0];
    const float* fp    = (const float*)d_in[1];
    const float* fn    = (const float*)d_in[2];
    const float* Wq    = (const float*)d_in[3];
    const float* Wk    = (const float*)d_in[4];
    const float* Wv    = (const float*)d_in[5];
    const float* Wo    = (const float*)d_in[6];
    const float* gamma = (const float*)d_in[7];
    const float* beta  = (const float*)d_in[8];
    float* out = (float*)d_out;

    char* ws = (char*)d_ws;
    bf16_t* Xn  = (bf16_t*)(ws);
    bf16_t* Qn  = (bf16_t*)(ws + 16777216);
    bf16_t* Kn  = (bf16_t*)(ws + 25165824);
    bf16_t* Xc  = (bf16_t*)(ws + 41943040);
    bf16_t* AOn = Xc;
    bf16_t* Vt  = (bf16_t*)(ws + 50331648);
    bf16_t* Wb  = (bf16_t*)(ws + 67108864);
    float*  Ssum = (float*)(ws + 69206016);
    float*  Ssq  = (float*)(ws + 69238784);
    float*  Zt  = (float*)(ws);

    prep_kernel<<<dim3(128, 24), 256, 0, stream>>>(fc, fp, fn, Xc, Xn);
    wcvt_kernel<<<dim3(256, 4), 256, 0, stream>>>(Wq, Wk, Wv, Wo, Wb, Ssum);
    qkv_kernel<<<dim3(160, 8), 256, 0, stream>>>(Xc, Xn, Wb, Qn, Kn, Vt);
    attn_kernel<<<dim3(1024), 256, 0, stream>>>(Qn, Kn, Vt, AOn);
    proj_kernel<<<dim3(32, 8), 256, 0, stream>>>(AOn, Wb, fc, Zt, Ssum, Ssq);
    apply_kernel<<<4096, 256, 0, stream>>>(Zt, Ssum, Ssq, gamma, beta, out);
}

// Round 19
// 207.524 us; speedup vs baseline: 1.0155x; 1.0155x over previous
//
#include <hip/hip_runtime.h>
#include <hip/hip_bf16.h>
#include <math.h>

#define NH 8
#define HD 64
#define CH 512
#define NT 1024
#define NB 8

typedef __bf16 bf16_t;
typedef bf16_t bf16x8 __attribute__((ext_vector_type(8)));
typedef bf16_t bf16x4 __attribute__((ext_vector_type(4)));
typedef float  f32x4  __attribute__((ext_vector_type(4)));
typedef float  f32x16 __attribute__((ext_vector_type(16)));
typedef unsigned u32x4 __attribute__((ext_vector_type(4)));

#define MFMA16(a, b, c) __builtin_amdgcn_mfma_f32_16x16x32_bf16((a), (b), (c), 0, 0, 0)
#define MFMA32(a, b, c) __builtin_amdgcn_mfma_f32_32x32x16_bf16((a), (b), (c), 0, 0, 0)
#define EXP2(x) __builtin_amdgcn_exp2f(x)

__device__ __forceinline__ void gload16(const void* g, void* l) {
    __builtin_amdgcn_global_load_lds(
        (const __attribute__((address_space(1))) void*)g,
        (__attribute__((address_space(3))) void*)l, 16, 0, 0);
}

// pack two f32 -> one dword of 2x bf16 (no builtin on gfx950; T12 recipe)
__device__ __forceinline__ unsigned cvtpk(float lo, float hi) {
    unsigned r;
    asm("v_cvt_pk_bf16_f32 %0, %1, %2" : "=v"(r) : "v"(lo), "v"(hi));
    return r;
}

// v_permlane32_swap_b32: a' = {a.lo32, b.lo32}, b' = {a.hi32, b.hi32}
__device__ __forceinline__ void plswap(unsigned& a, unsigned& b) {
    asm("v_permlane32_swap_b32 %0, %1" : "+v"(a), "+v"(b));
}

// ---------------------------------------------------------------------------
// prep: fp32 [C][N] -> bf16 [N][C] transpose (per 64x64 tile).
// grid (128, 24): x = tile (c-tile = x&7, n-tile = x>>3); y: b = y/3, ft = y%3
// ---------------------------------------------------------------------------
__global__ __launch_bounds__(256) void prep_kernel(
    const float* __restrict__ fc, const float* __restrict__ fp,
    const float* __restrict__ fn, bf16_t* __restrict__ Xc,
    bf16_t* __restrict__ Xn)
{
    __shared__ __align__(16) bf16_t tile[64 * 64];
    const int t = threadIdx.x;
    const int y = blockIdx.y;
    const int b = y / 3, ft = y % 3;
    const int c0 = (blockIdx.x & 7) * 64;
    const int n0 = (blockIdx.x >> 3) * 64;

    const float* src; bf16_t* dst;
    if (ft == 0)      { src = fc + (size_t)b * CH * NT; dst = Xc + (size_t)b * NT * CH; }
    else if (ft == 1) { src = fp + (size_t)b * CH * NT; dst = Xn + (size_t)b * 2 * NT * CH; }
    else              { src = fn + (size_t)b * CH * NT; dst = Xn + (size_t)b * 2 * NT * CH + (size_t)NT * CH; }

    const int nb = t & 15, cb = t >> 4;   // 4-wide chunks
    float4 ld[4];
#pragma unroll
    for (int i = 0; i < 4; ++i)
        ld[i] = *(const float4*)(src + (size_t)(c0 + cb * 4 + i) * NT + n0 + nb * 4);
    const float* lf = (const float*)ld;
#pragma unroll
    for (int j = 0; j < 4; ++j) {
        int n = nb * 4 + j;
        int v = (n >> 2) & 14;            // even -> bf16x8 readback stays contiguous
        bf16x4 wv = { (bf16_t)lf[0 * 4 + j], (bf16_t)lf[1 * 4 + j],
                      (bf16_t)lf[2 * 4 + j], (bf16_t)lf[3 * 4 + j] };
        *(bf16x4*)(tile + n * 64 + ((cb ^ v) * 4)) = wv;
    }
    __syncthreads();
#pragma unroll
    for (int i = 0; i < 2; ++i) {
        int gid = t + i * 256;            // 512 chunks of 16B
        int n = gid >> 3, c16 = gid & 7;
        int v = (n >> 2) & 14;
        bf16x8 val = *(const bf16x8*)(tile + n * 64 + (((2 * c16) ^ v) * 4));
        *(bf16x8*)(dst + (size_t)(n0 + n) * CH + c0 + c16 * 8) = val;
    }
}

// weights fp32 -> bf16, grid (256, 4); also zeroes the LN sum/sumsq buffers
__global__ __launch_bounds__(256) void wcvt_kernel(
    const float* __restrict__ Wq, const float* __restrict__ Wk,
    const float* __restrict__ Wv, const float* __restrict__ Wo,
    bf16_t* __restrict__ Wb, float* __restrict__ SQz)
{
    const int m = blockIdx.y;
    const float* src = (m == 0) ? Wq : (m == 1) ? Wk : (m == 2) ? Wv : Wo;
    bf16_t* dst = Wb + (size_t)m * CH * CH;
    int gid = blockIdx.x * 256 + threadIdx.x;      // 65536 float4 per matrix
    float4 v = *(const float4*)(src + (size_t)gid * 4);
    bf16x4 o = { (bf16_t)v.x, (bf16_t)v.y, (bf16_t)v.z, (bf16_t)v.w };
    *(bf16x4*)(dst + (size_t)gid * 4) = o;
    if (m == 0 && blockIdx.x < 16) {               // 16*256*16B = 64KB (sum+sumsq)
        f32x4 zz = {0.f, 0.f, 0.f, 0.f};
        *(f32x4*)(SQz + (size_t)(blockIdx.x * 256 + threadIdx.x) * 4) = zz;
    }
}

// ---------------------------------------------------------------------------
// gemm_core v6: 128x128 tile, K=512, BK=32, double-buffered LDS staging --
// ONE barrier per K-step: stage(kt+1) issued first, compute on buf[kt&1],
// barrier drains gloads + protects buffer reuse.  LDS: 4 x 8KB.
// ---------------------------------------------------------------------------
template <bool SWAP>
__device__ __forceinline__ void gemm_core(const bf16_t* __restrict__ A,
                                          const bf16_t* __restrict__ B,
                                          bf16_t* aT0, bf16_t* bT0,
                                          bf16_t* aT1, bf16_t* bT1,
                                          f32x4 acc[4][4])
{
    const int t = threadIdx.x, w = t >> 6, lane = t & 63;
    const int lid = lane & 15, quad = lane >> 4;
    const int wm = w >> 1, wn = w & 1;
    const int l4 = lane >> 2, k4 = lane & 3;

#define GSTAGE(k0, aT, bT)                                                     \
    {                                                                          \
        _Pragma("unroll")                                                      \
        for (int i = 0; i < 2; ++i) {                                          \
            int q = w * 2 + i;                       /* chunk 0..7 */          \
            int row = q * 16 + l4;                                             \
            int kk = k4 ^ ((row >> 1) & 3);                                    \
            gload16(A + (size_t)row * CH + (k0) + kk * 8, (aT) + q * 512);     \
            gload16(B + (size_t)row * CH + (k0) + kk * 8, (bT) + q * 512);     \
        }                                                                      \
    }

    GSTAGE(0, aT0, bT0);
    __syncthreads();

    for (int kt = 0; kt < 16; ++kt) {
        const int cur = kt & 1;
        const bf16_t* aTr = cur ? aT1 : aT0;
        const bf16_t* bTr = cur ? bT1 : bT0;
        if (kt < 15) {
            bf16_t* aTw = cur ? aT0 : aT1;
            bf16_t* bTw = cur ? bT0 : bT1;
            GSTAGE((kt + 1) * 32, aTw, bTw);
        }

        const bf16_t* mT = SWAP ? bTr : aTr;
        const bf16_t* nT = SWAP ? aTr : bTr;
        bf16x8 mf[4], nf[4];
#pragma unroll
        for (int i = 0; i < 4; ++i) {
            int row = wm * 64 + i * 16 + lid;
            int kw = quad ^ ((row >> 1) & 3);
            mf[i] = *(const bf16x8*)(mT + row * 32 + kw * 8);
        }
#pragma unroll
        for (int i = 0; i < 4; ++i) {
            int row = wn * 64 + i * 16 + lid;
            int kw = quad ^ ((row >> 1) & 3);
            nf[i] = *(const bf16x8*)(nT + row * 32 + kw * 8);
        }
        __builtin_amdgcn_s_setprio(1);
#pragma unroll
        for (int mi = 0; mi < 4; ++mi)
#pragma unroll
            for (int ni = 0; ni < 4; ++ni)
                acc[mi][ni] = MFMA16(mf[mi], nf[ni], acc[mi][ni]);
        __builtin_amdgcn_s_setprio(0);
        __syncthreads();   // drains next-tile gloads; buffers swap safely
    }
#undef GSTAGE
}

// ---------------------------------------------------------------------------
// qkv: grid (160, 8).  bx<32: Q; 32..95: K; 96..159: V (SWAP, writes Vt[co][key])
// ---------------------------------------------------------------------------
__global__ __launch_bounds__(256) void qkv_kernel(
    const bf16_t* __restrict__ Xc, const bf16_t* __restrict__ Xn,
    const bf16_t* __restrict__ Wb,
    bf16_t* __restrict__ Qn, bf16_t* __restrict__ Kn, bf16_t* __restrict__ Vt)
{
    __shared__ __align__(16) bf16_t aT0[128 * 32];
    __shared__ __align__(16) bf16_t bT0[128 * 32];
    __shared__ __align__(16) bf16_t aT1[128 * 32];
    __shared__ __align__(16) bf16_t bT1[128 * 32];
    const int bx = blockIdx.x, b = blockIdx.y;
    const int t = threadIdx.x, w = t >> 6, lane = t & 63;
    const int lid = lane & 15, quad = lane >> 4;
    const int wm = w >> 1, wn = w & 1;
    const float QSC = 0.125f * 1.44269504f;

    f32x4 acc[4][4] = {};

    if (bx < 96) {                        // Q or K job
        const bf16_t* A; const bf16_t* B; bf16_t* O; float scale;
        if (bx < 32) {
            int nt = bx >> 2, ct = bx & 3;
            A = Xc + (size_t)b * NT * CH + (size_t)nt * 128 * CH;
            B = Wb + (size_t)0 * CH * CH + (size_t)ct * 128 * CH;
            O = Qn + (size_t)b * NT * CH + (size_t)nt * 128 * CH + ct * 128;
            scale = QSC;
        } else {
            int j = bx - 32, nt = j >> 2, ct = j & 3;
            A = Xn + (size_t)b * 2 * NT * CH + (size_t)nt * 128 * CH;
            B = Wb + (size_t)1 * CH * CH + (size_t)ct * 128 * CH;
            O = Kn + (size_t)b * 2 * NT * CH + (size_t)nt * 128 * CH + ct * 128;
            scale = 1.0f;
        }
        gemm_core<false>(A, B, aT0, bT0, aT1, bT1, acc);
#pragma unroll
        for (int mi = 0; mi < 4; ++mi)
#pragma unroll
            for (int ni = 0; ni < 4; ++ni)
#pragma unroll
                for (int r = 0; r < 4; ++r) {
                    int n  = wm * 64 + mi * 16 + quad * 4 + r;
                    int co = wn * 64 + ni * 16 + lid;
                    O[(size_t)n * CH + co] = (bf16_t)(acc[mi][ni][r] * scale);
                }
    } else {                              // V job -> Vt[co][key]
        int j = bx - 96, nt = j >> 2, ct = j & 3;
        const bf16_t* A = Xn + (size_t)b * 2 * NT * CH + (size_t)nt * 128 * CH;
        const bf16_t* B = Wb + (size_t)2 * CH * CH + (size_t)ct * 128 * CH;
        bf16_t* O = Vt + (size_t)b * CH * 2 * NT + (size_t)ct * 128 * 2 * NT + nt * 128;
        gemm_core<true>(A, B, aT0, bT0, aT1, bT1, acc);
#pragma unroll
        for (int mi = 0; mi < 4; ++mi)
#pragma unroll
            for (int ni = 0; ni < 4; ++ni)
#pragma unroll
                for (int r = 0; r < 4; ++r) {
                    int co_l  = wm * 64 + mi * 16 + quad * 4 + r;
                    int key_l = wn * 64 + ni * 16 + lid;
                    O[(size_t)co_l * (2 * NT) + key_l] = (bf16_t)acc[mi][ni][r];
                }
    }
}

// ---------------------------------------------------------------------------
// attn v8: T3/T4 counted-vmcnt pipeline. Geometry = v7 (64-q blocks, 64-key
// tiles, 32 iters) but 3-deep KV buffers (48KB LDS, 3 blocks/CU) and raw
// s_barrier + s_waitcnt vmcnt(4): tile kt+2's loads stay in flight across
// the barrier; only tile kt+1's (already landed) are waited. Removes the
// per-iter vmcnt(0) drain that capped v5a/v7.
// ---------------------------------------------------------------------------
__global__ __launch_bounds__(256, 3) void attn_kernel(
    const bf16_t* __restrict__ Qn, const bf16_t* __restrict__ Kn,
    const bf16_t* __restrict__ Vt, bf16_t* __restrict__ AOn)
{
    __shared__ __align__(16) char smem[49152];
    bf16_t* const kb0 = (bf16_t*)smem;               // [64 key][64 d] each
    bf16_t* const kb1 = (bf16_t*)(smem + 8192);
    bf16_t* const kb2 = (bf16_t*)(smem + 16384);
    bf16_t* const vb0 = (bf16_t*)(smem + 24576);     // [64 d][64 key] each
    bf16_t* const vb1 = (bf16_t*)(smem + 32768);
    bf16_t* const vb2 = (bf16_t*)(smem + 40960);
    // epilogue overlays (used only after the main loop's final barrier):
    float*  const scr_all = (float*)smem;            // 2 x 2176 f32 (17408B)
    bf16_t* const obuf    = (bf16_t*)(smem + 17920); // [64][72] bf16 (9216B)
    float*  const l_scr   = (float*)(smem + 27136);  // 64 f32

    const int t = threadIdx.x;
    const int w = t >> 6, lane = t & 63;
    const int wq = w >> 1, wk = w & 1;
    const int l31 = lane & 31, h = lane >> 5;

    // grid 1024: all 16 q-tiles of one (b,h) share one XCD's L2.
    const int bid = blockIdx.x;
    const int xcd = bid & 7, ii = bid >> 3;          // ii: 0..127
    const int grp = xcd * 8 + (ii >> 4);             // 0..63
    const int qt  = ii & 15;
    const int b = grp >> 3, hh = grp & 7;
    const int q0 = qt * 64;

    const bf16_t* Qb  = Qn + ((size_t)b * NT + q0) * CH + hh * HD;
    const bf16_t* Kb  = Kn + (size_t)b * 2 * NT * CH + hh * HD;
    const bf16_t* Vtb = Vt + ((size_t)b * CH + hh * HD) * (2 * NT);
    bf16_t* AOb = AOn + ((size_t)b * NT + q0) * CH + hh * HD;

    // staging: 4 gload16 per thread per tile (2 K + 2 V)
#define STAGE_KV(kbn, kw, vw)                                                  \
    {                                                                          \
        _Pragma("unroll")                                                      \
        for (int i = 0; i < 2; ++i) {                                          \
            int ck = w * 64 + i * 256 + lane;                                  \
            int kr = ck >> 3, kg = ck & 7;                                     \
            gload16(Kb + (size_t)((kbn) + kr) * CH + ((kg ^ (kr & 7)) * 8),    \
                    (kw) + (w * 64 + i * 256) * 8);                            \
            gload16(Vtb + (size_t)kr * (2 * NT) + (kbn) + ((kg ^ (kr & 7)) * 8), \
                    (vw) + (w * 64 + i * 256) * 8);                            \
        }                                                                      \
    }

    // Q fragments: gathered once (one-time cost). wq picks 32-q half.
    const bf16_t* Qrow = Qb + (size_t)(wq * 32 + l31) * CH + h * 8;
    bf16x8 qf[4];
#pragma unroll
    for (int ks = 0; ks < 4; ++ks)
        qf[ks] = *(const bf16x8*)(Qrow + ks * 16);

    // prologue: stage tiles 0,1; wait tile0 only (tile1 stays in flight)
    STAGE_KV(0, kb0, vb0);
    STAGE_KV(64, kb1, vb1);
    asm volatile("s_waitcnt vmcnt(4)" ::: "memory");
    __builtin_amdgcn_s_barrier();
    __builtin_amdgcn_sched_barrier(0);

    // rotating buffers: kA = read (tile kt), kB = next (in flight/landed),
    // kC = stage target (tile kt+2)
    const bf16_t* kA = kb0; const bf16_t* vA = vb0;
    const bf16_t* kB = kb1; const bf16_t* vB = vb1;
    bf16_t* kC = kb2;       bf16_t* vC = vb2;

    f32x16 o[2] = {};          // [df] : d = df*32 + ...
    float lpart = 0.f;

    for (int kt = 0; kt < 32; ++kt) {
        // issue tile kt+2 into kC (last read in iter kt-1; safe)
        if (kt < 30)
            STAGE_KV((kt + 2) * 64, kC, vC);

        // ---- K fragments from LDS (swizzled b128 reads) ------------------
        const int krow = wk * 32 + l31;
        bf16x8 kfm[4];
#pragma unroll
        for (int ks = 0; ks < 4; ++ks)
            kfm[ks] = *(const bf16x8*)(kA + krow * 64 + (((ks * 2 + h) ^ (krow & 7)) * 8));

        f32x16 s = {};
        __builtin_amdgcn_s_setprio(1);
#pragma unroll
        for (int ks = 0; ks < 4; ++ks)
            s = MFMA32(kfm[ks], qf[ks], s);
        __builtin_amdgcn_s_setprio(0);

        // ---- softmax in registers -> PV B-fragments ----------------------
        float p[16];
#pragma unroll
        for (int r = 0; r < 16; ++r) p[r] = EXP2(s[r]);
        lpart += ((p[0] + p[1]) + (p[2] + p[3]))
               + ((p[4] + p[5]) + (p[6] + p[7]))
               + ((p[8] + p[9]) + (p[10] + p[11]))
               + ((p[12] + p[13]) + (p[14] + p[15]));
        unsigned a0 = cvtpk(p[0], p[1]),   b0 = cvtpk(p[4], p[5]);
        unsigned a1 = cvtpk(p[2], p[3]),   b1 = cvtpk(p[6], p[7]);
        unsigned a2 = cvtpk(p[8], p[9]),   b2 = cvtpk(p[12], p[13]);
        unsigned a3 = cvtpk(p[10], p[11]), b3 = cvtpk(p[14], p[15]);
        plswap(a0, b0); plswap(a1, b1); plswap(a2, b2); plswap(a3, b3);
        u32x4 f0 = { a0, a1, b0, b1 };
        u32x4 f1 = { a2, a3, b2, b3 };
        bf16x8 pfrag0 = __builtin_bit_cast(bf16x8, f0);
        bf16x8 pfrag1 = __builtin_bit_cast(bf16x8, f1);

        // ---- PV (V fragments from LDS); key = wk*32 + fi*16 + h*8 + e ----
        __builtin_amdgcn_s_setprio(1);
#pragma unroll
        for (int fi = 0; fi < 2; ++fi) {
            const bf16x8 pf = fi ? pfrag1 : pfrag0;
            bf16x8 av[2];
#pragma unroll
            for (int df = 0; df < 2; ++df) {
                int vrow = df * 32 + l31;
                int g = wk * 4 + fi * 2 + h;
                av[df] = *(const bf16x8*)(vA + vrow * 64 + ((g ^ (vrow & 7)) * 8));
            }
#pragma unroll
            for (int df = 0; df < 2; ++df)
                o[df] = MFMA32(av[df], pf, o[df]);
        }
        __builtin_amdgcn_s_setprio(0);

        // ---- counted-vmcnt barrier: wait tile kt+1 only ------------------
        if (kt < 31) {
            if (kt < 30)
                asm volatile("s_waitcnt vmcnt(4)" ::: "memory");
            else
                asm volatile("s_waitcnt vmcnt(0)" ::: "memory");
            __builtin_amdgcn_s_barrier();
            __builtin_amdgcn_sched_barrier(0);
        }

        // rotate buffers
        const bf16_t* tk = kA; kA = kB; kB = kC; kC = (bf16_t*)tk;
        const bf16_t* tv = vA; vA = vB; vB = vC; vC = (bf16_t*)tv;
    }
#undef STAGE_KV

    __syncthreads();   // all loads drained (vmcnt(0) at kt=30); sync for overlays

    // ---- epilogue: combine wk halves, normalize, store --------------------
    float l2 = lpart + __shfl_xor(lpart, 32);

    if (wk == 1) {
        float* scr = scr_all + wq * 2176;
#pragma unroll
        for (int df = 0; df < 2; ++df)
#pragma unroll
            for (int g = 0; g < 4; ++g) {
                int d = df * 32 + 8 * g + 4 * h;
                f32x4 v = { o[df][4 * g + 0], o[df][4 * g + 1],
                            o[df][4 * g + 2], o[df][4 * g + 3] };
                *(f32x4*)(scr + l31 * 68 + d) = v;
            }
        if (h == 0) l_scr[wq * 32 + l31] = l2;
    }
    __syncthreads();

    if (wk == 0) {
        const float* scr = scr_all + wq * 2176;
        float inv = 1.0f / (l2 + l_scr[wq * 32 + l31]);
#pragma unroll
        for (int df = 0; df < 2; ++df)
#pragma unroll
            for (int g = 0; g < 4; ++g) {
                int d = df * 32 + 8 * g + 4 * h;
                f32x4 part = *(const f32x4*)(scr + l31 * 68 + d);
                bf16x4 ov = {
                    (bf16_t)((o[df][4 * g + 0] + part.x) * inv),
                    (bf16_t)((o[df][4 * g + 1] + part.y) * inv),
                    (bf16_t)((o[df][4 * g + 2] + part.z) * inv),
                    (bf16_t)((o[df][4 * g + 3] + part.w) * inv) };
                int qg = wq * 32 + l31;
                *(bf16x4*)(obuf + qg * 72 + (d ^ (qg & 24))) = ov;
            }
    }
    __syncthreads();

#pragma unroll
    for (int i = 0; i < 2; ++i) {
        int gid = t + i * 256;            // 512 chunks: 64 rows x 8 granules
        int qr = gid >> 3, c8 = (gid & 7) * 8;
        *(bf16x8*)(AOb + (size_t)qr * CH + c8) =
            *(const bf16x8*)(obuf + qr * 72 + (c8 ^ (qr & 24)));
    }
}

// ---------------------------------------------------------------------------
// proj: Z^T[b][co][n] = (AO @ Wo^T)^T + f_curr[b][co][n]  (fp32). grid (32, 8)
// Fused LN stats: block reduces its 128-co slab per n, atomicAdd sum/sumsq.
// ---------------------------------------------------------------------------
__global__ __launch_bounds__(256) void proj_kernel(
    const bf16_t* __restrict__ AOn, const bf16_t* __restrict__ Wb,
    const float* __restrict__ fc, float* __restrict__ Zt,
    float* __restrict__ Ssum, float* __restrict__ Ssq)
{
    __shared__ __align__(16) bf16_t aT0[128 * 32];
    __shared__ __align__(16) bf16_t bT0[128 * 32];
    __shared__ __align__(16) bf16_t aT1[128 * 32];
    __shared__ __align__(16) bf16_t bT1[128 * 32];
    const int bx = blockIdx.x, b = blockIdx.y;
    const int nt = bx >> 2, ct = bx & 3;
    const int t = threadIdx.x, w = t >> 6, lane = t & 63;
    const int lid = lane & 15, quad = lane >> 4;
    const int wm = w >> 1, wn = w & 1;

    const bf16_t* A = AOn + (size_t)b * NT * CH + (size_t)nt * 128 * CH;
    const bf16_t* B = Wb + (size_t)3 * CH * CH + (size_t)ct * 128 * CH;   // Wo

    f32x4 acc[4][4] = {};
    gemm_core<true>(A, B, aT0, bT0, aT1, bT1, acc);

    const size_t bofs = (size_t)b * CH * NT;
    float sP[4] = {0.f, 0.f, 0.f, 0.f}, qP[4] = {0.f, 0.f, 0.f, 0.f};
#pragma unroll
    for (int mi = 0; mi < 4; ++mi)
#pragma unroll
        for (int ni = 0; ni < 4; ++ni)
#pragma unroll
            for (int r = 0; r < 4; ++r) {
                int co_l = wm * 64 + mi * 16 + quad * 4 + r;
                int n_l  = wn * 64 + ni * 16 + lid;
                size_t idx = bofs + (size_t)(ct * 128 + co_l) * NT + nt * 128 + n_l;
                float z = acc[mi][ni][r] + fc[idx];
                Zt[idx] = z;
                sP[ni] += z;
                qP[ni] += z * z;
            }
    // reduce over quad (co sub-blocks) within wave
#pragma unroll
    for (int ni = 0; ni < 4; ++ni) {
        sP[ni] += __shfl_xor(sP[ni], 16);  sP[ni] += __shfl_xor(sP[ni], 32);
        qP[ni] += __shfl_xor(qP[ni], 16);  qP[ni] += __shfl_xor(qP[ni], 32);
    }
    __syncthreads();                      // all frag reads of LDS done
    float* sRed = (float*)aT0;            // 256 f32
    float* qRed = sRed + 256;
    if (quad == 0) {
#pragma unroll
        for (int ni = 0; ni < 4; ++ni) {
            sRed[w * 64 + ni * 16 + lid] = sP[ni];
            qRed[w * 64 + ni * 16 + lid] = qP[ni];
        }
    }
    __syncthreads();
    if (t < 128) {                        // n_l = t; waves w=wn and w=2+wn
        float s = sRed[t] + sRed[128 + t];
        float q = qRed[t] + qRed[128 + t];
        atomicAdd(&Ssum[(size_t)b * NT + nt * 128 + t], s);
        atomicAdd(&Ssq [(size_t)b * NT + nt * 128 + t], q);
    }
}

// ---------------------------------------------------------------------------
// apply: out[b][co][n] = (z - mu[n]) * rs[n] * gamma[co] + beta[co].
// mu/rs computed inline from fused sum/sumsq.
// ---------------------------------------------------------------------------
__global__ __launch_bounds__(256) void apply_kernel(
    const float* __restrict__ Zt, const float* __restrict__ Ssum,
    const float* __restrict__ Ssq, const float* __restrict__ gamma,
    const float* __restrict__ beta, float* __restrict__ out)
{
    const int row = blockIdx.x;           // b*512 + co
    const int co = row & 511, b = row >> 9;
    const int t = threadIdx.x;
    const float g = gamma[co], be = beta[co];
    const size_t base = (size_t)row * NT + t * 4;
    f32x4 z  = *(const f32x4*)(Zt + base);
    f32x4 S  = *(const f32x4*)(Ssum + (size_t)b * NT + t * 4);
    f32x4 Q2 = *(const f32x4*)(Ssq  + (size_t)b * NT + t * 4);
    f32x4 o;
#pragma unroll
    for (int c = 0; c < 4; ++c) {
        float mu  = S[c] * (1.0f / 512.0f);
        float var = Q2[c] * (1.0f / 512.0f) - mu * mu;
        float rs  = rsqrtf(var + 1e-5f);
        o[c] = (z[c] - mu) * rs * g + be;
    }
    *(f32x4*)(out + base) = o;
}

// ---------------------------------------------------------------------------
extern "C" void kernel_launch(void* const* d_in, const int* in_sizes, int n_in,
                              void* d_out, int out_size, void* d_ws, size_t ws_size,
                              hipStream_t stream)
{
    (void)in_sizes; (void)n_in; (void)out_size; (void)ws_size;
    const float* fc    = (const float*)d_in[0];
    const float* fp    = (const float*)d_in[1];
    const float* fn    = (const float*)d_in[2];
    const float* Wq    = (const float*)d_in[3];
    const float* Wk    = (const float*)d_in[4];
    const float* Wv    = (const float*)d_in[5];
    const float* Wo    = (const float*)d_in[6];
    const float* gamma = (const float*)d_in[7];
    const float* beta  = (const float*)d_in[8];
    float* out = (float*)d_out;

    char* ws = (char*)d_ws;
    bf16_t* Xn  = (bf16_t*)(ws);
    bf16_t* Qn  = (bf16_t*)(ws + 16777216);
    bf16_t* Kn  = (bf16_t*)(ws + 25165824);
    bf16_t* Xc  = (bf16_t*)(ws + 41943040);
    bf16_t* AOn = Xc;
    bf16_t* Vt  = (bf16_t*)(ws + 50331648);
    bf16_t* Wb  = (bf16_t*)(ws + 67108864);
    float*  Ssum = (float*)(ws + 69206016);
    float*  Ssq  = (float*)(ws + 69238784);
    float*  Zt  = (float*)(ws);

    prep_kernel<<<dim3(128, 24), 256, 0, stream>>>(fc, fp, fn, Xc, Xn);
    wcvt_kernel<<<dim3(256, 4), 256, 0, stream>>>(Wq, Wk, Wv, Wo, Wb, Ssum);
    qkv_kernel<<<dim3(160, 8), 256, 0, stream>>>(Xc, Xn, Wb, Qn, Kn, Vt);
    attn_kernel<<<dim3(1024), 256, 0, stream>>>(Qn, Kn, Vt, AOn);
    proj_kernel<<<dim3(32, 8), 256, 0, stream>>>(AOn, Wb, fc, Zt, Ssum, Ssq);
    apply_kernel<<<4096, 256, 0, stream>>>(Zt, Ssum, Ssq, gamma, beta, out);
}